// Round 4
// baseline (167.530 us; speedup 1.0000x reference)
//
#include <hip/hip_runtime.h>
#include <math.h>

#define HW 4096          // 64*64
#define NB 8
#define NC 512
#define NCHUNK 8

// ---------------------------------------------------------------------------
// Kernel 1 (v5): LINEAR-STREAM partial 1x1 convs.
//
// History: v1-v4 (occupancy 9-32%, MLP 4-32 deep, fused or not) ALL pinned at
// 134 MB / 42 us = 3.2 TB/s effective read. Last untested axis: DRAM stream
// linearity. Previous variants strode 16 KB per channel step with only 1 KB
// wave-contiguity; write-only fills (linear) hit 6.27 TB/s. This version:
// block = (px-half, chunk, bz) so each block reads a contiguous 1 MB slab
// (64 planes x its 8 KB half-plane) near-linearly; thread owns 8 fixed pixels
// (2 x float4) and walks channels, 4-channel unroll = 8 float4 in flight.
//
// part layout (same as v1): part[(chunk*2+tensor)*32768 + b*4096 + hw]
// FP tree per pixel: per-chunk fold cc=0..63 in order (here), chunk-order
// left-fold + bias + relu in kernel 2 -> bit-identical to v1-v4 (absmax 0.0).
// ---------------------------------------------------------------------------
__global__ __launch_bounds__(256) void conv_partial(
    const float* __restrict__ fm, const float* __restrict__ x,
    const float* __restrict__ w1, const float* __restrict__ w2,
    float* __restrict__ part)
{
    const int t      = threadIdx.x;
    const int half   = blockIdx.x;                 // 0..1
    const int chunk  = blockIdx.y;                 // 0..7
    const int bz     = blockIdx.z;                 // b*2 + tensor
    const int b      = bz >> 1;
    const int tensor = bz & 1;
    const int c0     = chunk * 64;
    const int px     = half * 2048 + t * 8;        // 8 consecutive pixels

    const float* src = (tensor ? x : fm) + ((size_t)b * NC + c0) * HW + px;
    const float* w   = tensor ? w2 : w1;

    float4 a0 = make_float4(0.f, 0.f, 0.f, 0.f);
    float4 a1 = make_float4(0.f, 0.f, 0.f, 0.f);

    #pragma unroll
    for (int cb = 0; cb < 64; cb += 4) {
        float4 v[8];
        #pragma unroll
        for (int k = 0; k < 4; ++k) {
            const float* s = src + (size_t)(cb + k) * HW;
            v[2 * k]     = *(const float4*)(s);
            v[2 * k + 1] = *(const float4*)(s + 4);
        }
        #pragma unroll
        for (int k = 0; k < 4; ++k) {          // strict channel order
            const float wv = w[c0 + cb + k];
            a0.x = fmaf(v[2 * k].x,     wv, a0.x);
            a0.y = fmaf(v[2 * k].y,     wv, a0.y);
            a0.z = fmaf(v[2 * k].z,     wv, a0.z);
            a0.w = fmaf(v[2 * k].w,     wv, a0.w);
            a1.x = fmaf(v[2 * k + 1].x, wv, a1.x);
            a1.y = fmaf(v[2 * k + 1].y, wv, a1.y);
            a1.z = fmaf(v[2 * k + 1].z, wv, a1.z);
            a1.w = fmaf(v[2 * k + 1].w, wv, a1.w);
        }
    }

    float* p = part + ((size_t)(chunk * 2 + tensor) * NB + b) * HW + px;
    *(float4*)p       = a0;
    *((float4*)p + 1) = a1;
}

// ---------------------------------------------------------------------------
// Kernel 2: sum the 8 chunk partials, add bias, ReLU. (v1 verbatim)
// i = tensor*32768 + b*4096 + hw ; 65536 threads total.
// ---------------------------------------------------------------------------
__global__ __launch_bounds__(256) void reduce_bias_relu(
    const float* __restrict__ part,
    const float* __restrict__ b1, const float* __restrict__ b2,
    float* __restrict__ recon, float* __restrict__ refmap)
{
    const int i      = blockIdx.x * 256 + threadIdx.x;   // 0..65535
    const int tensor = i >> 15;                           // 0 or 1
    const int bhw    = i & 32767;

    float s = 0.f;
    #pragma unroll
    for (int ch = 0; ch < NCHUNK; ++ch)
        s += part[(size_t)(ch * 2 + tensor) * 32768 + bhw];

    const float bias = (tensor == 0) ? b1[0] : b2[0];
    const float r = fmaxf(s + bias, 0.f);
    if (tensor == 0) recon[bhw]  = r;
    else             refmap[bhw] = r;
}

// ---------------------------------------------------------------------------
// Kernel 3: correlation argmax + gather + fold. (unchanged)
// One wave per patch; 4 waves (4 patches) per block; 2048 blocks = 8 b * 256.
// gg in LDS: 65x65 zero-padded recon, stride 65 (bank = (p+q)%32, conflict-free).
// ---------------------------------------------------------------------------
__global__ __launch_bounds__(256) void correlate_gather(
    const float* __restrict__ recon, const float* __restrict__ refmap,
    float* __restrict__ out)
{
    __shared__ float gg[65 * 65];

    const int b     = blockIdx.x >> 8;          // 256 blocks per batch
    const int pbase = (blockIdx.x & 255) * 4;   // 4 patches per block
    const int t     = threadIdx.x;

    // stage zero-padded recon for this batch into LDS
    const float* rb = recon + (size_t)b * HW;
    for (int i = t; i < 65 * 65; i += 256) {
        const int r = i / 65;
        const int c = i - r * 65;
        gg[i] = (r < 64 && c < 64) ? rb[r * 64 + c] : 0.f;
    }
    __syncthreads();

    const int wave = t >> 6;
    const int lane = t & 63;
    const int l    = pbase + wave;       // patch index in [0,1024)
    const int ph   = l >> 5;
    const int pw   = l & 31;

    // 2x2 kernel from refmap patch l (wave-uniform addresses)
    const float* km = refmap + (size_t)b * HW + (ph * 2) * 64 + pw * 2;
    const float k00 = km[0], k01 = km[1], k10 = km[64], k11 = km[65];

    // lane handles window row p = lane; slide over q, reusing right->left
    const int p = lane;
    const float* row0 = gg + p * 65;
    const float* row1 = row0 + 65;

    float best = -INFINITY;
    int   bpos = 0;
    float a  = row0[0];
    float cv = row1[0];
    #pragma unroll
    for (int q = 0; q < 64; ++q) {
        const float bv = row0[q + 1];
        const float dv = row1[q + 1];
        // term order matches einsum reduction order (c, di, dj)
        float v = k00 * a;
        v = fmaf(k01, bv, v);
        v = fmaf(k10, cv, v);
        v = fmaf(k11, dv, v);
        const int pos = p * 64 + q;
        if (v > best) { best = v; bpos = pos; }   // strict > = first-max-wins within lane
        a  = bv;
        cv = dv;
    }

    // butterfly reduce across 64 lanes: max value, min position on ties
    #pragma unroll
    for (int m = 1; m < 64; m <<= 1) {
        const float ov = __shfl_xor(best, m, 64);
        const int   op = __shfl_xor(bpos, m, 64);
        if (ov > best || (ov == best && op < bpos)) { best = ov; bpos = op; }
    }

    if (lane == 0) {
        const int idx = bpos >> 2;       // offset // 4
        const int ph2 = idx >> 5;
        const int pw2 = idx & 31;
        const float* src = gg + (ph2 * 2) * 65 + pw2 * 2;   // recon patch idx
        float* o = out + (size_t)b * HW + (ph * 2) * 64 + pw * 2;
        o[0]  = src[0];
        o[1]  = src[1];
        o[64] = src[65];
        o[65] = src[66];
    }
}

// ---------------------------------------------------------------------------
extern "C" void kernel_launch(void* const* d_in, const int* in_sizes, int n_in,
                              void* d_out, int out_size, void* d_ws, size_t ws_size,
                              hipStream_t stream)
{
    const float* spade_fm = (const float*)d_in[0];
    const float* x        = (const float*)d_in[1];
    const float* w1       = (const float*)d_in[2];
    const float* b1       = (const float*)d_in[3];
    const float* w2       = (const float*)d_in[4];
    const float* b2       = (const float*)d_in[5];
    float* out = (float*)d_out;

    float* part   = (float*)d_ws;                 // 16 * 32768 floats = 2 MB
    float* recon  = part + 16 * 32768;            // 8*4096 floats
    float* refmap = recon + NB * HW;              // 8*4096 floats

    dim3 g1(2, NCHUNK, NB * 2);                   // 256 blocks, linear 1 MB/block
    conv_partial<<<g1, 256, 0, stream>>>(spade_fm, x, w1, w2, part);
    reduce_bias_relu<<<256, 256, 0, stream>>>(part, b1, b2, recon, refmap);
    correlate_gather<<<2048, 256, 0, stream>>>(recon, refmap, out);
}

// Round 5
// 165.876 us; speedup vs baseline: 1.0100x; 1.0100x over previous
//
#include <hip/hip_runtime.h>
#include <math.h>

#define HW 4096          // 64*64
#define NB 8
#define NC 512

// ---------------------------------------------------------------------------
// Kernel 1 (v4 verbatim): FUSED 1x1 convs + chunk-reduce + bias + ReLU.
// v1-v5 conv experiments (occupancy 9-32%, MLP 4-32 deep, fused, linear-slab)
// ALL pinned at 134 MB / ~42 us = 3.2 TB/s effective read -> read-path
// roofline. This fused form was the best-measured total (163.8 us).
//
// Bit-exactness: per pixel
//   s = 0; for chunk 0..7 { a = fold_{cc=0..63} fma(v,w,a) ; s += a } (+bias,relu)
// == original k1 (per-chunk fold, cc in order) + k2 (chunk-order left fold).
// ---------------------------------------------------------------------------
__global__ __launch_bounds__(256) void conv_reduce(
    const float* __restrict__ fm, const float* __restrict__ x,
    const float* __restrict__ w1, const float* __restrict__ w2,
    const float* __restrict__ b1, const float* __restrict__ b2,
    float* __restrict__ recon, float* __restrict__ refmap)
{
    const int t      = threadIdx.x;
    const int px     = blockIdx.x * 256 + t;       // pixel in [0,4096)
    const int bz     = blockIdx.y;                 // b*2 + tensor
    const int b      = bz >> 1;
    const int tensor = bz & 1;

    const float* src = (tensor ? x : fm) + (size_t)b * NC * HW + px;
    const float* w   = tensor ? w2 : w1;

    float s = 0.f;

    #pragma unroll
    for (int chunk = 0; chunk < 8; ++chunk) {
        float a = 0.f;
        #pragma unroll
        for (int half = 0; half < 2; ++half) {
            const int c0 = chunk * 64 + half * 32;
            float v[32];
            #pragma unroll
            for (int k = 0; k < 32; ++k)
                v[k] = src[(size_t)(c0 + k) * HW];
            #pragma unroll
            for (int k = 0; k < 32; ++k)
                a = fmaf(v[k], w[c0 + k], a);
        }
        s += a;          // chunk-order left fold == old reduce_bias_relu
    }

    const float bias = tensor ? b2[0] : b1[0];
    const float r = fmaxf(s + bias, 0.f);
    if (tensor == 0) recon[b * HW + px]  = r;
    else             refmap[b * HW + px] = r;
}

// ---------------------------------------------------------------------------
// Kernel 3 (v6): correlation argmax + gather, 4 patches per wave.
//
// Old: wave = 1 patch -> every wave re-read the whole 65x65 gg (128 scalar
// ds_read_b32), 256 blocks/batch re-staged the same 16.9 KB. LDS-issue-bound:
// inferred ~33 us (164 total - 43 conv - ~85 harness fills).
// New: the sliding windows (a,b,c,d) are IDENTICAL for all patches, so each
// wave scans the grid once and correlates 4 patches in registers. 16 patches
// per block -> 512 blocks: DS reads/patch /4, staging redundancy /4; VALU
// per patch unchanged; per-patch compare/tie-break logic bit-identical
// (pos = p*64+q, strict > within lane, min-pos-on-tie butterfly).
// gg stride 65: bank = (p+q)%32 -> 2-way on 64 lanes = free.
// ---------------------------------------------------------------------------
__global__ __launch_bounds__(256) void correlate_gather(
    const float* __restrict__ recon, const float* __restrict__ refmap,
    float* __restrict__ out)
{
    __shared__ float gg[65 * 65];

    const int b     = blockIdx.x >> 6;           // 64 blocks per batch
    const int pbase = (blockIdx.x & 63) * 16;    // 16 patches per block
    const int t     = threadIdx.x;

    // stage zero-padded recon for this batch into LDS
    const float* rb = recon + (size_t)b * HW;
    for (int i = t; i < 65 * 65; i += 256) {
        const int r = i / 65;
        const int c = i - r * 65;
        gg[i] = (r < 64 && c < 64) ? rb[r * 64 + c] : 0.f;
    }
    __syncthreads();

    const int wave = t >> 6;
    const int lane = t & 63;
    const int l0   = pbase + wave * 4;           // this wave's 4 patches

    // 2x2 kernels for 4 patches (wave-uniform addresses)
    float k00[4], k01[4], k10[4], k11[4];
    #pragma unroll
    for (int j = 0; j < 4; ++j) {
        const int l  = l0 + j;
        const int ph = l >> 5;
        const int pw = l & 31;
        const float* km = refmap + (size_t)b * HW + (ph * 2) * 64 + pw * 2;
        k00[j] = km[0]; k01[j] = km[1]; k10[j] = km[64]; k11[j] = km[65];
    }

    // lane handles window row p = lane; slide over q, reusing right->left
    const int p = lane;
    const float* row0 = gg + p * 65;
    const float* row1 = row0 + 65;

    float best[4] = { -INFINITY, -INFINITY, -INFINITY, -INFINITY };
    int   bpos[4] = { 0, 0, 0, 0 };
    float a  = row0[0];
    float cv = row1[0];
    #pragma unroll
    for (int q = 0; q < 64; ++q) {
        const float bv = row0[q + 1];
        const float dv = row1[q + 1];
        const int pos = p * 64 + q;
        #pragma unroll
        for (int j = 0; j < 4; ++j) {
            // term order matches einsum reduction order (c, di, dj)
            float v = k00[j] * a;
            v = fmaf(k01[j], bv, v);
            v = fmaf(k10[j], cv, v);
            v = fmaf(k11[j], dv, v);
            if (v > best[j]) { best[j] = v; bpos[j] = pos; }  // first-max within lane
        }
        a  = bv;
        cv = dv;
    }

    // butterfly reduce across 64 lanes: max value, min position on ties
    #pragma unroll
    for (int m = 1; m < 64; m <<= 1) {
        #pragma unroll
        for (int j = 0; j < 4; ++j) {
            const float ov = __shfl_xor(best[j], m, 64);
            const int   op = __shfl_xor(bpos[j], m, 64);
            if (ov > best[j] || (ov == best[j] && op < bpos[j])) {
                best[j] = ov; bpos[j] = op;
            }
        }
    }

    if (lane == 0) {
        #pragma unroll
        for (int j = 0; j < 4; ++j) {
            const int l   = l0 + j;
            const int idx = bpos[j] >> 2;    // offset // 4
            const int ph2 = idx >> 5;
            const int pw2 = idx & 31;
            const float* src = gg + (ph2 * 2) * 65 + pw2 * 2;   // recon patch idx
            float* o = out + (size_t)b * HW + ((l >> 5) * 2) * 64 + (l & 31) * 2;
            o[0]  = src[0];
            o[1]  = src[1];
            o[64] = src[65];
            o[65] = src[66];
        }
    }
}

// ---------------------------------------------------------------------------
extern "C" void kernel_launch(void* const* d_in, const int* in_sizes, int n_in,
                              void* d_out, int out_size, void* d_ws, size_t ws_size,
                              hipStream_t stream)
{
    const float* spade_fm = (const float*)d_in[0];
    const float* x        = (const float*)d_in[1];
    const float* w1       = (const float*)d_in[2];
    const float* b1       = (const float*)d_in[3];
    const float* w2       = (const float*)d_in[4];
    const float* b2       = (const float*)d_in[5];
    float* out = (float*)d_out;

    float* recon  = (float*)d_ws;                 // 8*4096 floats
    float* refmap = recon + NB * HW;              // 8*4096 floats

    dim3 g1(16, 16);                              // 256 blocks
    conv_reduce<<<g1, 256, 0, stream>>>(spade_fm, x, w1, w2, b1, b2, recon, refmap);
    correlate_gather<<<512, 256, 0, stream>>>(recon, refmap, out);
}